// Round 7
// baseline (496.633 us; speedup 1.0000x reference)
//
#include <hip/hip_runtime.h>
#include <stdint.h>

typedef unsigned short u16;
typedef _Float16 f16;
typedef _Float16 f16x8 __attribute__((ext_vector_type(8)));
typedef float    f32x4 __attribute__((ext_vector_type(4)));

#define HW   96
#define NPIX (HW*HW)      // 9216
#define BBATCH 2
#define NVIEW  5
#define NIMG 10

// LDS: double-buffered swizzled A tile (2 x 49 lines x 128 B = 12,544 B).
//   logical rows are 64 B (32 c f16); row-pairs packed into 128 B lines of
//   8 x 16 B chunks; chunk index XORed with (line&7) to spread banks (T2).
// Epilogue scratch needs 12,288 B -> LDS = 12,544 covers both.
#define ABUF 6272
#define LDS_BYTES (2*ABUF)

__device__ __forceinline__ int swz(int row, int chunk) {
    // byte offset of 16B chunk `chunk` (0..3) of logical 64B row `row`
    return ((row >> 1) << 7) + (((((row & 1) << 2) | chunk) ^ ((row >> 1) & 7)) << 4);
}

__device__ __forceinline__ u16 f16u(float f) {
    union { u16 u; f16 h; } v; v.h = (f16)f; return v.u;
}

// ---------- weight prep ----------
// Layout [cchunk][tap][o][c32] fp16 — one MFMA B-fragment (16 o x 16 B) is a
// fully coalesced 1024 B wave load (o-rows of 64 B contiguous). Round-6 PMC
// validated this layout (request-rate problem gone, FETCH dropped 162->126 MB).
__global__ __launch_bounds__(256)
void k_prep_w(const float* __restrict__ W1, const float* __restrict__ W2,
              const float* __restrict__ R1, const float* __restrict__ R2, const float* __restrict__ R3,
              u16* __restrict__ w1a, u16* __restrict__ w1b, u16* __restrict__ w2t,
              float* __restrict__ s1t, float* __restrict__ s2t, float* __restrict__ r3t)
{
    int id = blockIdx.x * 256 + threadIdx.x;
    if (id < 589824) {                       // w1a/w1b: [(c>>5)][t][o][c&31]
        int t = id >> 16; int r = id & 65535; int o = r >> 8; int c = r & 255;
        int kh = t / 3, kw = t % 3;
        const int dst = (((c >> 5) * 9 + t) * 256 + o) * 32 + (c & 31);
        *(f16*)&w1a[dst] = (f16)W1[((size_t)(o * 512 + c) * 3 + kh) * 3 + kw];
        *(f16*)&w1b[dst] = (f16)W1[((size_t)(o * 512 + 256 + c) * 3 + kh) * 3 + kw];
        return;
    }
    id -= 589824;
    if (id < 294912) {                       // w2t: [(c>>5)][t][o<128][c&31]
        int t = id >> 15; int r = id & 32767; int o = r >> 8; int c = r & 255;
        const int dst = (((c >> 5) * 9 + t) * 128 + o) * 32 + (c & 31);
        *(f16*)&w2t[dst] = (f16)W2[((size_t)(o * 256 + c) * 3 + t / 3) * 3 + (t % 3)];
        return;
    }
    id -= 294912;
    if (id < 288) {                          // s1t[t*32+o] = sum_i R1[o,i,kd,kh,1]
        int t = id >> 5; int o = id & 31;
        float s = 0.f;
        for (int i = 0; i < 64; ++i)
            s += R1[((size_t)((o * 64 + i) * 3 + t / 3) * 3 + t % 3) * 3 + 1];
        s1t[id] = s;
        return;
    }
    id -= 288;
    if (id < 4608) {                         // s2t[(t*32+i)*16+o] = R2[o,i,kd,kh,1]
        int o = id & 15; int r = id >> 4; int i = r & 31; int t = r >> 5;
        s2t[id] = R2[((size_t)((o * 32 + i) * 3 + t / 3) * 3 + t % 3) * 3 + 1];
        return;
    }
    id -= 4608;
    if (id < 1024) {                         // r3t[i*64+o] = R3[o,i]
        int o = id & 63; int i = id >> 6;
        r3t[id] = R3[(size_t)o * 16 + i];
    }
}

// ---------- NCHW f32 -> blocked f16 [img][row][cblk][px][32] ----------
__global__ __launch_bounds__(256)
void k_tr(const float* __restrict__ src, u16* __restrict__ dst, int img0, int imgMul)
{
    const int cblk = blockIdx.x, row = blockIdx.y, z = blockIdx.z;
    const int gimg = img0 + z * imgMul;
    const int tid = threadIdx.x;
    __shared__ u16 tile[96 * 40];            // [px][40], 80 B rows (16-aligned)
    const int c = tid >> 3, j = tid & 7;
    const float* s = src + ((size_t)(gimg * 256 + cblk * 32 + c)) * NPIX + (size_t)row * HW + j * 12;
    #pragma unroll
    for (int k = 0; k < 3; ++k) {
        const float4 v = ((const float4*)s)[k];
        const int px = j * 12 + k * 4;
        tile[(px + 0) * 40 + c] = f16u(v.x);
        tile[(px + 1) * 40 + c] = f16u(v.y);
        tile[(px + 2) * 40 + c] = f16u(v.z);
        tile[(px + 3) * 40 + c] = f16u(v.w);
    }
    __syncthreads();
    if (tid < 192) {
        const int px = tid >> 1, part = tid & 1;   // 32 B each
        const uint4 v0 = ((const uint4*)(tile + px * 40 + part * 16))[0];
        const uint4 v1 = ((const uint4*)(tile + px * 40 + part * 16))[1];
        uint4* d = (uint4*)(dst + ((((size_t)z * HW + row) * 8 + cblk) * HW + px) * 32 + part * 16);
        d[0] = v0; d[1] = v1;
    }
}

// ---------- MFMA 3x3 conv ----------
// Combination of the two individually-validated halves:
//  - B fragments direct-to-register from the COALESCED [cchunk][tap][o][c32]
//    table (round 6: fixed the 512-B-strided request-rate wall of rounds 1/3/4)
//  - register double-buffer bf0/bf1 + LDS-dbuf A with ONE barrier per body
//    (round-3 skeleton: prefetches issued at top of body(i) have the whole
//    compute phase (~600 cyc > 350 cyc L2 lat) before the end-of-body drain;
//    round 6 exposed the full latency every iter by issuing same-iter).
// MODE 0: in=feats2 (y=batch), out refp img y. no bias/relu.
// MODE 1: in=feats chunk (y), + refp[batch] + b1 + relu -> x1 img y.  gimg=ib+y.
// MODE 2: in=x1 (y), + b2 + relu, fused W3-dot -> pv[ib+y].
// 256 thr = 4 waves (wm px-half, wn o-half); block tile 96 px x 128 o.
template<int MODE>
__global__ __launch_bounds__(256, 2)
void k_conv(const u16* __restrict__ in, const u16* __restrict__ wt,
            const u16* __restrict__ refp, const float* __restrict__ bias,
            const float* __restrict__ W3, void* __restrict__ outp, int ib)
{
    constexpr int Cout = (MODE == 2) ? 128 : 256;
    const int nwgY = gridDim.y;
    const int bid = blockIdx.x + HW * (blockIdx.y + nwgY * blockIdx.z);
    const int nwg = HW * nwgY * gridDim.z;
    const int wk  = (bid & 7) * (nwg >> 3) + (bid >> 3);   // neutral (measured) XCD remap
    const int h   = wk % HW;
    const int yz  = wk / HW;
    const int y   = yz % nwgY;
    const int ob  = (yz / nwgY) * 128;
    const int tid = threadIdx.x;
    const int wv = tid >> 6, l = tid & 63;
    const int wm = wv >> 1, wn = wv & 1;
    const int lane16 = l & 15, quad = l >> 4;

    __shared__ __align__(16) char lds[LDS_BYTES];
    char* const bufA = lds;
    char* const bufB = lds + ABUF;

    f32x4 acc[3][4];
    #pragma unroll
    for (int mf = 0; mf < 3; ++mf)
        #pragma unroll
        for (int nf = 0; nf < 4; ++nf) acc[mf][nf] = (f32x4){0.f, 0.f, 0.f, 0.f};

    // valid input rows (block-uniform); taps base = (dh+1)*3
    int hh0 = 0, hh1 = 0, hh2 = 0, tb0 = 0, tb1 = 0, tb2 = 0, nv = 0;
    #pragma unroll
    for (int dh = -1; dh <= 1; ++dh) {
        const int q = h + dh;
        if ((unsigned)q < (unsigned)HW) {
            if (nv == 0)      { hh0 = q; tb0 = (dh + 1) * 3; }
            else if (nv == 1) { hh1 = q; tb1 = (dh + 1) * 3; }
            else              { hh2 = q; tb2 = (dh + 1) * 3; }
            ++nv;
        }
    }
    const int NIT = nv * 8;                 // always even (16 or 24)
    auto hsel = [&](int k) { return k == 0 ? hh0 : (k == 1 ? hh1 : hh2); };
    auto tsel = [&](int k) { return k == 0 ? tb0 : (k == 1 ? tb1 : tb2); };

    // per-lane weight base: o-row (ob + wn*64 + lane16), c-slice quad*8 f16
    const u16* const wq = wt + (size_t)(ob + wn * 64 + lane16) * 32 + quad * 8;

    const int spx = tid >> 1, shalf = tid & 1;
    uint4 sA, sB;
    f16x8 bf0[12], bf1[12];

    auto loadB = [&](int j, f16x8 (&bf)[12]) {
        const int kk = j >> 3, c0 = (j & 7) * 32;
        const u16* const ws = wq + (size_t)(((c0 >> 5) * 9 + tsel(kk)) * Cout) * 32;
        #pragma unroll
        for (int dw = 0; dw < 3; ++dw)
            #pragma unroll
            for (int nf = 0; nf < 4; ++nf)
                bf[dw * 4 + nf] = *(const f16x8*)(ws + (dw * Cout + nf * 16) * 32);
    };

    // prologue: stage tile 0 into bufA; zero halo rows (0,97) of both buffers;
    // load B fragments for iter 0.
    if (tid < 192) {
        const uint4* g = (const uint4*)(in +
            ((((size_t)y * HW + hsel(0)) * 8 + 0) * HW + spx) * 32 + shalf * 16);
        sA = g[0]; sB = g[1];
        *(uint4*)(bufA + swz(spx + 1, shalf * 2))     = sA;
        *(uint4*)(bufA + swz(spx + 1, shalf * 2 + 1)) = sB;
    }
    if (tid < 64) {
        char* b = (tid & 32) ? bufB : bufA;
        const int base = (tid & 16) ? (48 * 128 + 64) : 0;
        ((unsigned int*)(b + base))[tid & 15] = 0u;
    }
    loadB(0, bf0);
    __syncthreads();

    auto body = [&](int i, const char* buf, char* nbuf,
                    const f16x8 (&bfc)[12], f16x8 (&bfn)[12]) {
        const bool pf = (i + 1 < NIT);
        if (pf && tid < 192) {               // A prefetch: issue FIRST (oldest
            const int j = i + 1;             // vmem -> A ds_write waits vmcnt(12))
            const int kj = j >> 3, cj = (j & 7) * 32;
            const uint4* g = (const uint4*)(in +
                ((((size_t)y * HW + hsel(kj)) * 8 + (cj >> 5)) * HW + spx) * 32 + shalf * 16);
            sA = g[0]; sB = g[1];
        }
        if (pf) loadB(i + 1, bfn);           // B prefetch: coalesced 1024 B loads
        #pragma unroll
        for (int dw = 0; dw < 3; ++dw) {
            f16x8 af[3];
            #pragma unroll
            for (int mf = 0; mf < 3; ++mf)
                af[mf] = *(const f16x8*)(buf + swz(wm * 48 + mf * 16 + lane16 + dw, quad));
            #pragma unroll
            for (int nf = 0; nf < 4; ++nf)
                #pragma unroll
                for (int mf = 0; mf < 3; ++mf)
                    acc[mf][nf] = __builtin_amdgcn_mfma_f32_16x16x32_f16(af[mf], bfc[dw * 4 + nf], acc[mf][nf], 0, 0, 0);
        }
        if (pf && tid < 192) {               // write next A tile late
            *(uint4*)(nbuf + swz(spx + 1, shalf * 2))     = sA;
            *(uint4*)(nbuf + swz(spx + 1, shalf * 2 + 1)) = sB;
        }
        __syncthreads();                     // B(i+1) landed during compute; drain ~free
    };

    for (int i = 0; i < NIT; i += 2) {       // static ping-pong (regs + LDS)
        body(i,     bufA, bufB, bf0, bf1);
        body(i + 1, bufB, bufA, bf1, bf0);
    }

    if (MODE <= 1) {
        // ---- LDS-transpose epilogue -> blocked f16 [img][row][cblk][px][32] ----
        const int rimg = (MODE == 1) ? (ib + y) / NVIEW : 0;
        float bias4[4] = {0.f, 0.f, 0.f, 0.f};
        if (MODE == 1) {
            #pragma unroll
            for (int nf = 0; nf < 4; ++nf) bias4[nf] = bias[ob + wn * 64 + nf * 16 + lane16];
        }
        char* epi = lds + wv * 3072;                 // 48 px x 32 o f16 per wave
        u16* outg = (u16*)outp;
        #pragma unroll
        for (int p = 0; p < 2; ++p) {
            __syncthreads();
            #pragma unroll
            for (int nn = 0; nn < 2; ++nn) {
                const int nf = p * 2 + nn;
                #pragma unroll
                for (int mf = 0; mf < 3; ++mf)
                    #pragma unroll
                    for (int r = 0; r < 4; ++r) {
                        const int pxl = mf * 16 + quad * 4 + r;
                        *(u16*)(epi + pxl * 64 + (nn * 16 + lane16) * 2) =
                            f16u(acc[mf][nf][r] + bias4[nf]);
                    }
            }
            __syncthreads();
            const int cblk = (ob + wn * 64 + p * 32) >> 5;
            const size_t obase = (((size_t)y * HW + h) * 8 + cblk) * (size_t)(HW * 32);
            const size_t rbase = (((size_t)rimg * HW + h) * 8 + cblk) * (size_t)(HW * 32);
            #pragma unroll
            for (int i = 0; i < 3; ++i) {
                const int u = i * 64 + l;            // 0..191
                const int pxl = u >> 2, part = u & 3;
                f16x8 v = *(const f16x8*)(epi + pxl * 64 + part * 16);
                const int px = wm * 48 + pxl;
                if (MODE == 1) {
                    const f16x8 rv = *(const f16x8*)(refp + rbase + (size_t)px * 32 + part * 8);
                    #pragma unroll
                    for (int jj = 0; jj < 8; ++jj)
                        v[jj] = (f16)fmaxf((float)v[jj] + (float)rv[jj], 0.f);
                }
                *(f16x8*)(outg + obase + (size_t)px * 32 + part * 8) = v;
            }
        }
    } else {
        // ---- fused cost epilogue: pv[gimg][hw] = sum_o W3[o]*relu(acc+b2[o]) ----
        const int gimg = ib + y;
        float w3v[4], b2v[4];
        #pragma unroll
        for (int nf = 0; nf < 4; ++nf) {
            const int o = wn * 64 + nf * 16 + lane16;
            w3v[nf] = W3[o]; b2v[nf] = bias[o];
        }
        float s[3][4];
        #pragma unroll
        for (int mf = 0; mf < 3; ++mf)
            #pragma unroll
            for (int r = 0; r < 4; ++r) {
                float t = 0.f;
                #pragma unroll
                for (int nf = 0; nf < 4; ++nf)
                    t += w3v[nf] * fmaxf(acc[mf][nf][r] + b2v[nf], 0.f);
                s[mf][r] = t;
            }
        #pragma unroll
        for (int xb = 1; xb < 16; xb <<= 1)
            #pragma unroll
            for (int mf = 0; mf < 3; ++mf)
                #pragma unroll
                for (int r = 0; r < 4; ++r)
                    s[mf][r] += __shfl_xor(s[mf][r], xb);
        __syncthreads();
        float* cs = (float*)lds;
        if (wn == 0 && lane16 == 0) {
            #pragma unroll
            for (int mf = 0; mf < 3; ++mf)
                #pragma unroll
                for (int r = 0; r < 4; ++r)
                    cs[wm * 48 + mf * 16 + quad * 4 + r] = s[mf][r];
        }
        __syncthreads();
        if (wn == 1 && lane16 == 0) {
            float* pvp = (float*)outp + (size_t)gimg * NPIX + (size_t)h * HW;
            #pragma unroll
            for (int mf = 0; mf < 3; ++mf)
                #pragma unroll
                for (int r = 0; r < 4; ++r) {
                    const int px = wm * 48 + mf * 16 + quad * 4 + r;
                    pvp[px] = cs[px] + s[mf][r];
                }
        }
    }
}

// ---------- mean over 5 views + b3 ----------
__global__ __launch_bounds__(256)
void k_cost_sum(const float* __restrict__ pv, const float* __restrict__ b3, float* __restrict__ ca)
{
    const int id = blockIdx.x * 256 + threadIdx.x;
    if (id >= BBATCH * NPIX) return;
    const int b = id / NPIX, hw = id % NPIX;
    float s = 0.f;
    #pragma unroll
    for (int n = 0; n < NVIEW; ++n) s += pv[(size_t)(b * NVIEW + n) * NPIX + hw];
    ca[id] = b3[0] + 0.2f * s;
}

// ---------- collapsed 3D stage 1: 1->32ch 3x3 ----------
__global__ __launch_bounds__(256)
void k_d1(const float* __restrict__ cost_agg, const float* __restrict__ s1t,
          const float* __restrict__ rb1, float* __restrict__ t1)
{
    const int id = blockIdx.x * 256 + threadIdx.x;   // [b][hw][o], o<32
    const int o = id & 31; const int r = id >> 5;
    const int hw = r % NPIX; const int bimg = r / NPIX;
    const int y = hw / HW, x = hw % HW;
    const float* ca = cost_agg + (size_t)bimg * NPIX;
    float s = rb1[o];
    #pragma unroll
    for (int t = 0; t < 9; ++t) {
        const int yy = y + t / 3 - 1, xx = x + t % 3 - 1;
        if ((unsigned)yy < HW && (unsigned)xx < HW)
            s += s1t[t * 32 + o] * ca[yy * HW + xx];
    }
    t1[id] = fmaxf(s, 0.f);
}

// ---------- collapsed 3D stage 2: 32->16ch 3x3 ----------
__global__ __launch_bounds__(256)
void k_d2(const float* __restrict__ t1, const float* __restrict__ s2t,
          const float* __restrict__ rb2, float* __restrict__ t2)
{
    const int id = blockIdx.x * 256 + threadIdx.x;   // [b][hw][o], o<16
    const int o = id & 15; const int r = id >> 4;
    const int hw = r % NPIX; const int bimg = r / NPIX;
    const int y = hw / HW, x = hw % HW;
    float s = rb2[o];
    for (int t = 0; t < 9; ++t) {
        const int yy = y + t / 3 - 1, xx = x + t % 3 - 1;
        if ((unsigned)yy < HW && (unsigned)xx < HW) {
            const float* tp = t1 + ((size_t)bimg * NPIX + yy * HW + xx) * 32;
            #pragma unroll
            for (int i = 0; i < 32; ++i)
                s += s2t[(t * 32 + i) * 16 + o] * tp[i];
        }
    }
    t2[id] = fmaxf(s, 0.f);
}

// ---------- 1x1 16->64 + softmax + both outputs (f32) ----------
__global__ __launch_bounds__(256)
void k_d3(const float* __restrict__ t2, const float* __restrict__ r3t,
          const float* __restrict__ rb3, float* __restrict__ out)
{
    const int wv = threadIdx.x >> 6, o = threadIdx.x & 63;
    const int pix = blockIdx.x * 4 + wv;     // [b][hw]
    const float* tp = t2 + (size_t)pix * 16;
    float cv = rb3[o];
    #pragma unroll
    for (int i = 0; i < 16; ++i) cv += r3t[i * 64 + o] * tp[i];
    const float z = -cv;
    float m = z;
    #pragma unroll
    for (int off = 32; off; off >>= 1) m = fmaxf(m, __shfl_xor(m, off));
    const float e = __expf(z - m);
    float s = e;
    #pragma unroll
    for (int off = 32; off; off >>= 1) s += __shfl_xor(s, off);
    const float p = e / s;
    const size_t idx = (size_t)pix * 64 + o;
    out[idx] = cv;
    out[idx + (size_t)BBATCH * NPIX * 64] = p;
}

extern "C" void kernel_launch(void* const* d_in, const int* in_sizes, int n_in,
                              void* d_out, int out_size, void* d_ws, size_t ws_size,
                              hipStream_t stream)
{
    (void)in_sizes; (void)n_in; (void)out_size;
    const float* focal = (const float*)d_in[0];
    const float* W1  = (const float*)d_in[3];
    const float* b1  = (const float*)d_in[4];
    const float* W2  = (const float*)d_in[5];
    const float* b2  = (const float*)d_in[6];
    const float* W3  = (const float*)d_in[7];
    const float* b3  = (const float*)d_in[8];
    const float* R1  = (const float*)d_in[9];
    const float* rb1 = (const float*)d_in[10];
    const float* R2  = (const float*)d_in[11];
    const float* rb2 = (const float*)d_in[12];
    const float* R3  = (const float*)d_in[13];
    const float* rb3 = (const float*)d_in[14];

    char* ws = (char*)d_ws;
    size_t off = 0;
    auto alloc = [&](size_t sz) { char* p = ws + off; off = (off + sz + 255) & ~(size_t)255; return p; };
    const size_t IMG = (size_t)HW * 8 * HW * 32 * 2;       // 4,718,592 B (blocked f16 img)
    u16*   w1a  = (u16*)  alloc(1179648);
    u16*   w1b  = (u16*)  alloc(1179648);
    u16*   w2t  = (u16*)  alloc(589824);
    float* s1t  = (float*)alloc(1152);
    float* s2t  = (float*)alloc(18432);
    float* r3t  = (float*)alloc(4096);
    float* ca   = (float*)alloc(73728);
    float* t1   = (float*)alloc(2359296);
    float* t2   = (float*)alloc(1179648);
    float* pv   = (float*)alloc(NIMG * NPIX * 4);          // 368,640
    u16*   refp   = (u16*)alloc(BBATCH * IMG);             // 9,437,184
    u16*   feats2 = (u16*)alloc(BBATCH * IMG);             // 9,437,184
    const size_t base = off;                               // ~25.9 MB
    int C = 1;
    if (base + 20 * IMG + 512 <= ws_size)      C = 10;
    else if (base + 10 * IMG + 512 <= ws_size) C = 5;
    else if (base + 4 * IMG + 512 <= ws_size)  C = 2;
    u16* feats = (u16*)alloc((size_t)C * IMG);
    u16* x1    = (u16*)alloc((size_t)C * IMG);

    k_prep_w<<<(890656 + 255) / 256, 256, 0, stream>>>(W1, W2, R1, R2, R3, w1a, w1b, w2t, s1t, s2t, r3t);

    // transpose the two reference images (n=0 of each batch) and run the ref half of conv1
    k_tr<<<dim3(8, HW, BBATCH), 256, 0, stream>>>(focal, feats2, 0, NVIEW);
    k_conv<0><<<dim3(HW, BBATCH, 2), 256, 0, stream>>>(feats2, w1b, nullptr, nullptr, nullptr, refp, 0);

    for (int ib = 0; ib < NIMG; ib += C) {
        k_tr<<<dim3(8, HW, C), 256, 0, stream>>>(focal, feats, ib, 1);
        k_conv<1><<<dim3(HW, C, 2), 256, 0, stream>>>(feats, w1a, refp, b1, nullptr, x1, ib);
        k_conv<2><<<dim3(HW, C, 1), 256, 0, stream>>>(x1, w2t, nullptr, b2, W3, pv, ib);
    }

    k_cost_sum<<<(BBATCH * NPIX + 255) / 256, 256, 0, stream>>>(pv, b3, ca);
    k_d1<<<(BBATCH * NPIX * 32) / 256, 256, 0, stream>>>(ca, s1t, rb1, t1);
    k_d2<<<(BBATCH * NPIX * 16) / 256, 256, 0, stream>>>(t1, s2t, rb2, t2);
    k_d3<<<(BBATCH * NPIX) / 4, 256, 0, stream>>>(t2, r3t, rb3, (float*)d_out);
}

// Round 9
// 425.740 us; speedup vs baseline: 1.1665x; 1.1665x over previous
//
#include <hip/hip_runtime.h>
#include <stdint.h>

typedef unsigned short u16;
typedef _Float16 f16;
typedef _Float16 f16x8 __attribute__((ext_vector_type(8)));
typedef float    f32x4 __attribute__((ext_vector_type(4)));

#define HW   96
#define NPIX (HW*HW)      // 9216
#define BBATCH 2
#define NVIEW  5
#define NIMG 10

// LDS layout (XOR-swizzled, T2-style):
//   logical tiles have 64 B rows (32 c f16); row-pairs are packed into 128 B lines
//   of 8 x 16 B chunks; chunk index is XORed with (line&7) to spread banks.
//   A tile: rows 0..97 (96 px + 2 halo) -> 49 lines x 128 B = 6272 B @0
//   B tile: rows 0..383 (3 dw-taps x 128 o) -> 192 lines x 128 B = 24576 B @6272
// Staging is done with global_load_lds width=16 (rule #21: LINEAR dest segments,
// per-lane INVERSE-SWIZZLED global source), so there are no explicit ds_writes.
#define LDS_B_OFF 6272
#define LDS_BYTES (6272 + 24576)

__device__ __forceinline__ int swz(int row, int chunk) {
    // byte offset of 16B chunk `chunk` (0..3) of logical 64B row `row`
    return ((row >> 1) << 7) + (((((row & 1) << 2) | chunk) ^ ((row >> 1) & 7)) << 4);
}

__device__ __forceinline__ void gl16(const u16* g, char* l) {
    __builtin_amdgcn_global_load_lds(
        (const __attribute__((address_space(1))) void*)g,
        (__attribute__((address_space(3))) void*)l, 16, 0, 0);
}

__device__ __forceinline__ u16 f16u(float f) {
    union { u16 u; f16 h; } v; v.h = (f16)f; return v.u;
}

// ---------- weight prep ----------
// Layout [cchunk][tap][o][c32] fp16 (round-6 validated): each 1024 B LDS staging
// segment reads a contiguous 1024 B region of this table -> perfectly coalesced
// global_load_lds sources.
__global__ __launch_bounds__(256)
void k_prep_w(const float* __restrict__ W1, const float* __restrict__ W2,
              const float* __restrict__ R1, const float* __restrict__ R2, const float* __restrict__ R3,
              u16* __restrict__ w1a, u16* __restrict__ w1b, u16* __restrict__ w2t,
              float* __restrict__ s1t, float* __restrict__ s2t, float* __restrict__ r3t)
{
    int id = blockIdx.x * 256 + threadIdx.x;
    if (id < 589824) {                       // w1a/w1b: [(c>>5)][t][o][c&31]
        int t = id >> 16; int r = id & 65535; int o = r >> 8; int c = r & 255;
        int kh = t / 3, kw = t % 3;
        const int dst = (((c >> 5) * 9 + t) * 256 + o) * 32 + (c & 31);
        *(f16*)&w1a[dst] = (f16)W1[((size_t)(o * 512 + c) * 3 + kh) * 3 + kw];
        *(f16*)&w1b[dst] = (f16)W1[((size_t)(o * 512 + 256 + c) * 3 + kh) * 3 + kw];
        return;
    }
    id -= 589824;
    if (id < 294912) {                       // w2t: [(c>>5)][t][o<128][c&31]
        int t = id >> 15; int r = id & 32767; int o = r >> 8; int c = r & 255;
        const int dst = (((c >> 5) * 9 + t) * 128 + o) * 32 + (c & 31);
        *(f16*)&w2t[dst] = (f16)W2[((size_t)(o * 256 + c) * 3 + t / 3) * 3 + (t % 3)];
        return;
    }
    id -= 294912;
    if (id < 288) {                          // s1t[t*32+o] = sum_i R1[o,i,kd,kh,1]
        int t = id >> 5; int o = id & 31;
        float s = 0.f;
        for (int i = 0; i < 64; ++i)
            s += R1[((size_t)((o * 64 + i) * 3 + t / 3) * 3 + t % 3) * 3 + 1];
        s1t[id] = s;
        return;
    }
    id -= 288;
    if (id < 4608) {                         // s2t[(t*32+i)*16+o] = R2[o,i,kd,kh,1]
        int o = id & 15; int r = id >> 4; int i = r & 31; int t = r >> 5;
        s2t[id] = R2[((size_t)((o * 32 + i) * 3 + t / 3) * 3 + t % 3) * 3 + 1];
        return;
    }
    id -= 4608;
    if (id < 1024) {                         // r3t[i*64+o] = R3[o,i]
        int o = id & 63; int i = id >> 6;
        r3t[id] = R3[(size_t)o * 16 + i];
    }
}

// ---------- NCHW f32 -> blocked f16 [img][row][cblk][px][32] ----------
__global__ __launch_bounds__(256)
void k_tr(const float* __restrict__ src, u16* __restrict__ dst, int img0, int imgMul)
{
    const int cblk = blockIdx.x, row = blockIdx.y, z = blockIdx.z;
    const int gimg = img0 + z * imgMul;
    const int tid = threadIdx.x;
    __shared__ u16 tile[96 * 40];            // [px][40], 80 B rows (16-aligned)
    const int c = tid >> 3, j = tid & 7;
    const float* s = src + ((size_t)(gimg * 256 + cblk * 32 + c)) * NPIX + (size_t)row * HW + j * 12;
    #pragma unroll
    for (int k = 0; k < 3; ++k) {
        const float4 v = ((const float4*)s)[k];
        const int px = j * 12 + k * 4;
        tile[(px + 0) * 40 + c] = f16u(v.x);
        tile[(px + 1) * 40 + c] = f16u(v.y);
        tile[(px + 2) * 40 + c] = f16u(v.z);
        tile[(px + 3) * 40 + c] = f16u(v.w);
    }
    __syncthreads();
    if (tid < 192) {
        const int px = tid >> 1, part = tid & 1;   // 32 B each
        const uint4 v0 = ((const uint4*)(tile + px * 40 + part * 16))[0];
        const uint4 v1 = ((const uint4*)(tile + px * 40 + part * 16))[1];
        uint4* d = (uint4*)(dst + ((((size_t)z * HW + row) * 8 + cblk) * HW + px) * 32 + part * 16);
        d[0] = v0; d[1] = v1;
    }
}

// ---------- MFMA 3x3 conv (round-2 structure + global_load_lds staging) ----------
// Round-2 base (136 us MODE1, 4 blocks/CU) with the ONE proven staging change:
// all A/B staging via __builtin_amdgcn_global_load_lds width=16. Removes 30
// ds_write wave-ops + 30 VALU-issued loads + staging VGPRs + the tid<192
// divergence per block-iter. Dest segments are linear 1024 B; the XOR-swizzle
// is realized by per-lane inverse-swizzled SOURCE offsets (precomputed,
// loop-invariant). Reg-B variants (r1/3/4/6/7, 169-301 us) are abandoned:
// cooperative staging + 4-block TLP beats intra-wave prefetch on this op.
// MODE 0: in=feats2 (y=batch), out refp img y. no bias/relu.
// MODE 1: in=feats chunk (y), + refp[batch] + b1 + relu -> x1 img y.  gimg=ib+y.
// MODE 2: in=x1 (y), + b2 + relu, fused W3-dot -> pv[ib+y].
// 256 thr = 4 waves (wm px-half, wn o-half); block tile 96 px x 128 o.
template<int MODE>
__global__ __launch_bounds__(256, 4)
void k_conv(const u16* __restrict__ in, const u16* __restrict__ wt,
            const u16* __restrict__ refp, const float* __restrict__ bias,
            const float* __restrict__ W3, void* __restrict__ outp, int ib)
{
    constexpr int Cout = (MODE == 2) ? 128 : 256;
    const int h  = blockIdx.x;
    const int y  = blockIdx.y;
    const int ob = blockIdx.z * 128;
    const int tid = threadIdx.x;
    const int wv = tid >> 6, l = tid & 63;
    const int wm = wv >> 1, wn = wv & 1;
    const int lane16 = l & 15, quad = l >> 4;

    __shared__ __align__(16) char lds[LDS_BYTES];

    f32x4 acc[3][4];
    #pragma unroll
    for (int mf = 0; mf < 3; ++mf)
        #pragma unroll
        for (int nf = 0; nf < 4; ++nf) acc[mf][nf] = (f32x4){0.f, 0.f, 0.f, 0.f};

    // ---- per-lane inverse-swizzle source offsets (loop-invariant) ----
    // A: 6 segments of 1024 B at lds[64 + 1024k); wave w owns k=w and k=w+4 (w<2).
    //    lds off 64+1024k+16l -> logical row/chunk -> src elem (row-1)*32+chunk*8.
    int aoff[2] = {0, 0};
    #pragma unroll
    for (int j = 0; j < 2; ++j) {
        const int k = wv + 4 * j;
        if (k < 6) {
            const int t4 = 4 + l;
            const int ln8 = t4 >> 3;                 // 0..8
            const int cpp = (t4 & 7) ^ (ln8 & 7);
            const int row = 16 * k + 2 * ln8 + (cpp >> 2);
            aoff[j] = (row - 1) * 32 + (cpp & 3) * 8;
        }
    }
    // B: 24 segments at lds[LDS_B_OFF + 1024m); wave w owns m = w + 4j, j=0..5.
    //    row = 16m + 2*(l>>3) + (cpp>>2), cpp = (l&7)^(l>>3); dwt=row>>7, o=row&127.
    int boff[6];
    {
        const int cpp = (l & 7) ^ (l >> 3);
        #pragma unroll
        for (int j = 0; j < 6; ++j) {
            const int m = wv + 4 * j;
            const int row = 16 * m + 2 * (l >> 3) + (cpp >> 2);
            const int dwt = row >> 7, oo = row & 127;
            boff[j] = (dwt * Cout + ob + oo) * 32 + (cpp & 3) * 8;
        }
    }

    // zero halo rows 0 and 97 (64 B each; swizzle is identity for these chunks)
    if (tid < 32) {
        const int base = (tid & 16) ? (48 * 128 + 64) : 0;
        ((unsigned int*)(lds + base))[tid & 15] = 0u;
    }

    for (int dh = -1; dh <= 1; ++dh) {
        const int hh = h + dh;
        if ((unsigned)hh >= (unsigned)HW) continue;   // block-uniform
        const int tb = (dh + 1) * 3;
        for (int c0 = 0; c0 < 256; c0 += 32) {
            __syncthreads();
            // ---- stage A: 6 x global_load_lds(16) ----
            {
                const size_t abase = ((((size_t)y * HW + hh) * 8 + (c0 >> 5)) * (size_t)HW) * 32;
                gl16(in + abase + aoff[0], lds + 64 + 1024 * wv);
                if (wv < 2)
                    gl16(in + abase + aoff[1], lds + 64 + 1024 * (wv + 4));
            }
            // ---- stage B: 24 x global_load_lds(16) ----
            {
                const size_t bbase = (size_t)((c0 >> 5) * 9 + tb) * Cout * 32;
                #pragma unroll
                for (int j = 0; j < 6; ++j)
                    gl16(wt + bbase + boff[j], lds + LDS_B_OFF + 1024 * (wv + 4 * j));
            }
            __syncthreads();                 // vmcnt(0) drain -> LDS ready
            // ---- compute: per dw, 3 A-frags + 4 B-frags -> 12 MFMAs ----
            #pragma unroll
            for (int dw = 0; dw < 3; ++dw) {
                f16x8 af[3];
                #pragma unroll
                for (int mf = 0; mf < 3; ++mf)
                    af[mf] = *(const f16x8*)(lds + swz(wm * 48 + mf * 16 + lane16 + dw, quad));
                #pragma unroll
                for (int nf = 0; nf < 4; ++nf) {
                    const f16x8 bf = *(const f16x8*)(lds + LDS_B_OFF +
                        swz(dw * 128 + wn * 64 + nf * 16 + lane16, quad));
                    #pragma unroll
                    for (int mf = 0; mf < 3; ++mf)
                        acc[mf][nf] = __builtin_amdgcn_mfma_f32_16x16x32_f16(af[mf], bf, acc[mf][nf], 0, 0, 0);
                }
            }
        }
    }

    if (MODE <= 1) {
        // ---- LDS-transpose epilogue -> blocked f16 [img][row][cblk][px][32] ----
        const int rimg = (MODE == 1) ? (ib + y) / NVIEW : 0;
        float bias4[4] = {0.f, 0.f, 0.f, 0.f};
        if (MODE == 1) {
            #pragma unroll
            for (int nf = 0; nf < 4; ++nf) bias4[nf] = bias[ob + wn * 64 + nf * 16 + lane16];
        }
        char* epi = lds + wv * 3072;                 // 48 px x 32 o f16 per wave
        u16* outg = (u16*)outp;
        #pragma unroll
        for (int p = 0; p < 2; ++p) {
            __syncthreads();
            #pragma unroll
            for (int nn = 0; nn < 2; ++nn) {
                const int nf = p * 2 + nn;
                #pragma unroll
                for (int mf = 0; mf < 3; ++mf)
                    #pragma unroll
                    for (int r = 0; r < 4; ++r) {
                        const int pxl = mf * 16 + quad * 4 + r;
                        *(u16*)(epi + pxl * 64 + (nn * 16 + lane16) * 2) =
                            f16u(acc[mf][nf][r] + bias4[nf]);
                    }
            }
            __syncthreads();
            const int cblk = (ob + wn * 64 + p * 32) >> 5;
            const size_t obase = (((size_t)y * HW + h) * 8 + cblk) * (size_t)(HW * 32);
            const size_t rbase = (((size_t)rimg * HW + h) * 8 + cblk) * (size_t)(HW * 32);
            #pragma unroll
            for (int i = 0; i < 3; ++i) {
                const int u = i * 64 + l;            // 0..191
                const int pxl = u >> 2, part = u & 3;
                f16x8 v = *(const f16x8*)(epi + pxl * 64 + part * 16);
                const int px = wm * 48 + pxl;
                if (MODE == 1) {
                    const f16x8 rv = *(const f16x8*)(refp + rbase + (size_t)px * 32 + part * 8);
                    #pragma unroll
                    for (int jj = 0; jj < 8; ++jj)
                        v[jj] = (f16)fmaxf((float)v[jj] + (float)rv[jj], 0.f);
                }
                *(f16x8*)(outg + obase + (size_t)px * 32 + part * 8) = v;
            }
        }
    } else {
        // ---- fused cost epilogue: pv[gimg][hw] = sum_o W3[o]*relu(acc+b2[o]) ----
        const int gimg = ib + y;
        float w3v[4], b2v[4];
        #pragma unroll
        for (int nf = 0; nf < 4; ++nf) {
            const int o = wn * 64 + nf * 16 + lane16;
            w3v[nf] = W3[o]; b2v[nf] = bias[o];
        }
        float s[3][4];
        #pragma unroll
        for (int mf = 0; mf < 3; ++mf)
            #pragma unroll
            for (int r = 0; r < 4; ++r) {
                float t = 0.f;
                #pragma unroll
                for (int nf = 0; nf < 4; ++nf)
                    t += w3v[nf] * fmaxf(acc[mf][nf][r] + b2v[nf], 0.f);
                s[mf][r] = t;
            }
        #pragma unroll
        for (int xb = 1; xb < 16; xb <<= 1)
            #pragma unroll
            for (int mf = 0; mf < 3; ++mf)
                #pragma unroll
                for (int r = 0; r < 4; ++r)
                    s[mf][r] += __shfl_xor(s[mf][r], xb);
        __syncthreads();
        float* cs = (float*)lds;
        if (wn == 0 && lane16 == 0) {
            #pragma unroll
            for (int mf = 0; mf < 3; ++mf)
                #pragma unroll
                for (int r = 0; r < 4; ++r)
                    cs[wm * 48 + mf * 16 + quad * 4 + r] = s[mf][r];
        }
        __syncthreads();
        if (wn == 1 && lane16 == 0) {
            float* pvp = (float*)outp + (size_t)gimg * NPIX + (size_t)h * HW;
            #pragma unroll
            for (int mf = 0; mf < 3; ++mf)
                #pragma unroll
                for (int r = 0; r < 4; ++r) {
                    const int px = wm * 48 + mf * 16 + quad * 4 + r;
                    pvp[px] = cs[px] + s[mf][r];
                }
        }
    }
}

// ---------- mean over 5 views + b3 ----------
__global__ __launch_bounds__(256)
void k_cost_sum(const float* __restrict__ pv, const float* __restrict__ b3, float* __restrict__ ca)
{
    const int id = blockIdx.x * 256 + threadIdx.x;
    if (id >= BBATCH * NPIX) return;
    const int b = id / NPIX, hw = id % NPIX;
    float s = 0.f;
    #pragma unroll
    for (int n = 0; n < NVIEW; ++n) s += pv[(size_t)(b * NVIEW + n) * NPIX + hw];
    ca[id] = b3[0] + 0.2f * s;
}

// ---------- collapsed 3D stage 1: 1->32ch 3x3 ----------
__global__ __launch_bounds__(256)
void k_d1(const float* __restrict__ cost_agg, const float* __restrict__ s1t,
          const float* __restrict__ rb1, float* __restrict__ t1)
{
    const int id = blockIdx.x * 256 + threadIdx.x;   // [b][hw][o], o<32
    const int o = id & 31; const int r = id >> 5;
    const int hw = r % NPIX; const int bimg = r / NPIX;
    const int y = hw / HW, x = hw % HW;
    const float* ca = cost_agg + (size_t)bimg * NPIX;
    float s = rb1[o];
    #pragma unroll
    for (int t = 0; t < 9; ++t) {
        const int yy = y + t / 3 - 1, xx = x + t % 3 - 1;
        if ((unsigned)yy < HW && (unsigned)xx < HW)
            s += s1t[t * 32 + o] * ca[yy * HW + xx];
    }
    t1[id] = fmaxf(s, 0.f);
}

// ---------- collapsed 3D stage 2: 32->16ch 3x3 ----------
__global__ __launch_bounds__(256)
void k_d2(const float* __restrict__ t1, const float* __restrict__ s2t,
          const float* __restrict__ rb2, float* __restrict__ t2)
{
    const int id = blockIdx.x * 256 + threadIdx.x;   // [b][hw][o], o<16
    const int o = id & 15; const int r = id >> 4;
    const int hw = r % NPIX; const int bimg = r / NPIX;
    const int y = hw / HW, x = hw % HW;
    float s = rb2[o];
    for (int t = 0; t < 9; ++t) {
        const int yy = y + t / 3 - 1, xx = x + t % 3 - 1;
        if ((unsigned)yy < HW && (unsigned)xx < HW) {
            const float* tp = t1 + ((size_t)bimg * NPIX + yy * HW + xx) * 32;
            #pragma unroll
            for (int i = 0; i < 32; ++i)
                s += s2t[(t * 32 + i) * 16 + o] * tp[i];
        }
    }
    t2[id] = fmaxf(s, 0.f);
}

// ---------- 1x1 16->64 + softmax + both outputs (f32) ----------
__global__ __launch_bounds__(256)
void k_d3(const float* __restrict__ t2, const float* __restrict__ r3t,
          const float* __restrict__ rb3, float* __restrict__ out)
{
    const int wv = threadIdx.x >> 6, o = threadIdx.x & 63;
    const int pix = blockIdx.x * 4 + wv;     // [b][hw]
    const float* tp = t2 + (size_t)pix * 16;
    float cv = rb3[o];
    #pragma unroll
    for (int i = 0; i < 16; ++i) cv += r3t[i * 64 + o] * tp[i];
    const float z = -cv;
    float m = z;
    #pragma unroll
    for (int off = 32; off; off >>= 1) m = fmaxf(m, __shfl_xor(m, off));
    const float e = __expf(z - m);
    float s = e;
    #pragma unroll
    for (int off = 32; off; off >>= 1) s += __shfl_xor(s, off);
    const float p = e / s;
    const size_t idx = (size_t)pix * 64 + o;
    out[idx] = cv;
    out[idx + (size_t)BBATCH * NPIX * 64] = p;
}

extern "C" void kernel_launch(void* const* d_in, const int* in_sizes, int n_in,
                              void* d_out, int out_size, void* d_ws, size_t ws_size,
                              hipStream_t stream)
{
    (void)in_sizes; (void)n_in; (void)out_size;
    const float* focal = (const float*)d_in[0];
    const float* W1  = (const float*)d_in[3];
    const float* b1  = (const float*)d_in[4];
    const float* W2  = (const float*)d_in[5];
    const float* b2  = (const float*)d_in[6];
    const float* W3  = (const float*)d_in[7];
    const float* b3  = (const float*)d_in[8];
    const float* R1  = (const float*)d_in[9];
    const float* rb1 = (const float*)d_in[10];
    const float* R2  = (const float*)d_in[11];
    const float* rb2 = (const float*)d_in[12];
    const float* R3  = (const float*)d_in[13];
    const float* rb3 = (const float*)d_in[14];

    char* ws = (char*)d_ws;
    size_t off = 0;
    auto alloc = [&](size_t sz) { char* p = ws + off; off = (off + sz + 255) & ~(size_t)255; return p; };
    const size_t IMG = (size_t)HW * 8 * HW * 32 * 2;       // 4,718,592 B (blocked f16 img)
    u16*   w1a  = (u16*)  alloc(1179648);
    u16*   w1b  = (u16*)  alloc(1179648);
    u16*   w2t  = (u16*)  alloc(589824);
    float* s1t  = (float*)alloc(1152);
    float* s2t  = (float*)alloc(18432);
    float* r3t  = (float*)alloc(4096);
    float* ca   = (float*)alloc(73728);
    float* t1   = (float*)alloc(2359296);
    float* t2   = (float*)alloc(1179648);
    float* pv   = (float*)alloc(NIMG * NPIX * 4);          // 368,640
    u16*   refp   = (u16*)alloc(BBATCH * IMG);             // 9,437,184
    u16*   feats2 = (u16*)alloc(BBATCH * IMG);             // 9,437,184
    const size_t base = off;                               // ~25.9 MB
    int C = 1;
    if (base + 20 * IMG + 512 <= ws_size)      C = 10;
    else if (base + 10 * IMG + 512 <= ws_size) C = 5;
    else if (base + 4 * IMG + 512 <= ws_size)  C = 2;
    u16* feats = (u16*)alloc((size_t)C * IMG);
    u16* x1    = (u16*)alloc((size_t)C * IMG);

    k_prep_w<<<(890656 + 255) / 256, 256, 0, stream>>>(W1, W2, R1, R2, R3, w1a, w1b, w2t, s1t, s2t, r3t);

    // transpose the two reference images (n=0 of each batch) and run the ref half of conv1
    k_tr<<<dim3(8, HW, BBATCH), 256, 0, stream>>>(focal, feats2, 0, NVIEW);
    k_conv<0><<<dim3(HW, BBATCH, 2), 256, 0, stream>>>(feats2, w1b, nullptr, nullptr, nullptr, refp, 0);

    for (int ib = 0; ib < NIMG; ib += C) {
        k_tr<<<dim3(8, HW, C), 256, 0, stream>>>(focal, feats, ib, 1);
        k_conv<1><<<dim3(HW, C, 2), 256, 0, stream>>>(feats, w1a, refp, b1, nullptr, x1, ib);
        k_conv<2><<<dim3(HW, C, 1), 256, 0, stream>>>(x1, w2t, nullptr, b2, W3, pv, ib);
    }

    k_cost_sum<<<(BBATCH * NPIX + 255) / 256, 256, 0, stream>>>(pv, b3, ca);
    k_d1<<<(BBATCH * NPIX * 32) / 256, 256, 0, stream>>>(ca, s1t, rb1, t1);
    k_d2<<<(BBATCH * NPIX * 16) / 256, 256, 0, stream>>>(t1, s2t, rb2, t2);
    k_d3<<<(BBATCH * NPIX) / 4, 256, 0, stream>>>(t2, r3t, rb3, (float*)d_out);
}